// Round 3
// baseline (426.366 us; speedup 1.0000x reference)
//
#include <hip/hip_runtime.h>

#define B_ 8
#define T_ 8192
#define D_ 1024
#define GD_ 64
#define WSZ_ 16
#define NWIN_ (T_ / WSZ_)   // 512

// ---------------------------------------------------------------------------
// K1 (fused, 1-wave blocks): sims of g = normalize(relu(z@W1)@W2).
// Block = 64 tokens x 64 gd, 64 threads (one wave), microtile 8 tok x 8 gd.
// z tile stored TRANSPOSED in LDS (Zst[k][tok]) so all compute reads are
// ds_read_b128. No barriers needed (single wave, in-order LDS).
// Precision: f32 FMA within 64-long K chunks, f64 accumulation across
// chunks (validated in R1/R2: zero pick flips vs numpy f32 reference).
// ---------------------------------------------------------------------------
__global__ __launch_bounds__(64) void k_sims(
    const float* __restrict__ z, const float* __restrict__ W1,
    const float* __restrict__ W2, double* __restrict__ sims_out)
{
  __shared__ float Zst[64][65];   // phase A: z^T chunk [k][tok];
                                  // later: H^T [gd][tok]; then G [tok][gd]
  __shared__ float Ws[64][64];    // W1 chunk [k][gd]; later W2 [gd][gd']

  const int tid = threadIdx.x;
  const int ts = tid >> 3;        // 0..7 -> tokens 8*ts..8*ts+7
  const int gs = tid & 7;         // 0..7 -> gd 8*gs..8*gs+7
  const long bt0 = (long)blockIdx.x * 64;

  double acc64[8][8];
#pragma unroll
  for (int i = 0; i < 8; ++i)
#pragma unroll
    for (int j = 0; j < 8; ++j) acc64[i][j] = 0.0;

  const int ld_tok = tid >> 4;    // 0..3 (+4*it)
  const int ld_c4 = tid & 15;     // 0..15 -> k quad

  for (int k0 = 0; k0 < D_; k0 += 64) {
    // ---- stage z transposed: Zst[k][tok] (coalesced global, scalar writes)
#pragma unroll
    for (int it = 0; it < 16; ++it) {
      const int tok = ld_tok + 4 * it;
      const float4 v =
          *(const float4*)(z + (bt0 + tok) * D_ + k0 + 4 * ld_c4);
      Zst[4 * ld_c4 + 0][tok] = v.x;
      Zst[4 * ld_c4 + 1][tok] = v.y;
      Zst[4 * ld_c4 + 2][tok] = v.z;
      Zst[4 * ld_c4 + 3][tok] = v.w;
    }
    // ---- stage W1 chunk: Ws[k][gd] (row-major copy, b128 both ways)
#pragma unroll
    for (int it = 0; it < 16; ++it) {
      const int idx = it * 64 + tid;            // 0..1023 -> float4 index
      const int row = idx >> 4, cq = idx & 15;
      *(float4*)&Ws[row][4 * cq] =
          *(const float4*)(W1 + (k0 + row) * GD_ + 4 * cq);
    }

    float accf[8][8];
#pragma unroll
    for (int i = 0; i < 8; ++i)
#pragma unroll
      for (int j = 0; j < 8; ++j) accf[i][j] = 0.0f;

#pragma unroll 4
    for (int k = 0; k < 64; ++k) {
      const float4 a0 = *(const float4*)&Zst[k][8 * ts];
      const float4 a1 = *(const float4*)&Zst[k][8 * ts + 4];
      const float4 b0 = *(const float4*)&Ws[k][8 * gs];
      const float4 b1 = *(const float4*)&Ws[k][8 * gs + 4];
      const float zz[8] = {a0.x, a0.y, a0.z, a0.w, a1.x, a1.y, a1.z, a1.w};
      const float ww[8] = {b0.x, b0.y, b0.z, b0.w, b1.x, b1.y, b1.z, b1.w};
#pragma unroll
      for (int i = 0; i < 8; ++i)
#pragma unroll
        for (int j = 0; j < 8; ++j)
          accf[i][j] = fmaf(zz[i], ww[j], accf[i][j]);
    }
#pragma unroll
    for (int i = 0; i < 8; ++i)
#pragma unroll
      for (int j = 0; j < 8; ++j) acc64[i][j] += (double)accf[i][j];
  }

  // ---- H = relu(.), f32-rounded, stored TRANSPOSED: Zst[gd][tok]
#pragma unroll
  for (int j = 0; j < 8; ++j) {
    float4 h0, h1;
    float hv[8];
#pragma unroll
    for (int i = 0; i < 8; ++i) {
      const double h = acc64[i][j] > 0.0 ? acc64[i][j] : 0.0;
      hv[i] = (float)h;
    }
    h0.x = hv[0]; h0.y = hv[1]; h0.z = hv[2]; h0.w = hv[3];
    h1.x = hv[4]; h1.y = hv[5]; h1.z = hv[6]; h1.w = hv[7];
    *(float4*)&Zst[8 * gs + j][8 * ts] = h0;
    *(float4*)&Zst[8 * gs + j][8 * ts + 4] = h1;
  }
  // ---- stage W2 into Ws
#pragma unroll
  for (int it = 0; it < 16; ++it) {
    const int idx = it * 64 + tid;
    const int row = idx >> 4, cq = idx & 15;
    *(float4*)&Ws[row][4 * cq] = *(const float4*)(W2 + row * GD_ + 4 * cq);
  }

  // ---- phase B: G = H @ W2 (single f32 chunk, K=64; same as R1/R2)
  float acc2[8][8];
#pragma unroll
  for (int i = 0; i < 8; ++i)
#pragma unroll
    for (int j = 0; j < 8; ++j) acc2[i][j] = 0.0f;
#pragma unroll 4
  for (int k = 0; k < 64; ++k) {
    const float4 a0 = *(const float4*)&Zst[k][8 * ts];
    const float4 a1 = *(const float4*)&Zst[k][8 * ts + 4];
    const float4 b0 = *(const float4*)&Ws[k][8 * gs];
    const float4 b1 = *(const float4*)&Ws[k][8 * gs + 4];
    const float hh[8] = {a0.x, a0.y, a0.z, a0.w, a1.x, a1.y, a1.z, a1.w};
    const float ww[8] = {b0.x, b0.y, b0.z, b0.w, b1.x, b1.y, b1.z, b1.w};
#pragma unroll
    for (int i = 0; i < 8; ++i)
#pragma unroll
      for (int j = 0; j < 8; ++j)
        acc2[i][j] = fmaf(hh[i], ww[j], acc2[i][j]);
  }

  // ---- normalize: f64 row norm of f32-rounded G (reduce over 8 gs lanes)
#pragma unroll
  for (int i = 0; i < 8; ++i) {
    double ss = 0.0;
#pragma unroll
    for (int j = 0; j < 8; ++j)
      ss += (double)acc2[i][j] * (double)acc2[i][j];
#pragma unroll
    for (int m = 1; m < 8; m <<= 1) ss += __shfl_xor(ss, m);
    const double denom = sqrt(ss) + 1e-8;
    float gv[8];
#pragma unroll
    for (int j = 0; j < 8; ++j)
      gv[j] = (float)((double)acc2[i][j] / denom);
    float4 g0, g1;
    g0.x = gv[0]; g0.y = gv[1]; g0.z = gv[2]; g0.w = gv[3];
    g1.x = gv[4]; g1.y = gv[5]; g1.z = gv[6]; g1.w = gv[7];
    // write G row-major into Zst[tok][gd] (all Hst reads are done)
    *(float4*)&Zst[8 * ts + i][8 * gs] = g0;
    *(float4*)&Zst[8 * ts + i][8 * gs + 4] = g1;
  }

  // ---- sims: 4 windows x 15 edges; one thread per edge, f64 dot
  if (tid < 4 * (WSZ_ - 1)) {
    const int w = tid / (WSZ_ - 1), e = tid % (WSZ_ - 1);
    const int t = w * WSZ_ + e;
    double s = 0.0;
#pragma unroll 8
    for (int d = 0; d < GD_; ++d)
      s += (double)Zst[t][d] * (double)Zst[t + 1][d];
    sims_out[((long)blockIdx.x * 4 + w) * (WSZ_ - 1) + e] = s;
  }
}

// ---------------------------------------------------------------------------
// K2: per-window stable sort + budgeted greedy pick. 1 thread per window.
// ---------------------------------------------------------------------------
__global__ __launch_bounds__(64) void k_pick(
    const double* __restrict__ sims, const int* __restrict__ tlptr,
    int* __restrict__ mrMask, int* __restrict__ keptCnt)
{
  const int win = blockIdx.x * 64 + threadIdx.x;
  if (win >= B_ * NWIN_) return;
  const int w = win % NWIN_;

  const int tl = tlptr[0];
  const int mn = T_ - tl;
  const int base = mn / NWIN_, extra = mn % NWIN_;
  int budget = base + (w < extra ? 1 : 0);
  if (budget > WSZ_ / 2) budget = WSZ_ / 2;
  if (budget < 0) budget = 0;

  double v[WSZ_ - 1];
  int id[WSZ_ - 1];
  for (int e = 0; e < WSZ_ - 1; ++e) {
    v[e] = sims[(long)win * (WSZ_ - 1) + e];
    id[e] = e;
  }
  for (int i = 1; i < WSZ_ - 1; ++i) {
    const double dv = v[i]; const int di = id[i];
    int j = i - 1;
    while (j >= 0 && v[j] < dv) { v[j + 1] = v[j]; id[j + 1] = id[j]; --j; }
    v[j + 1] = dv; id[j + 1] = di;
  }
  bool used[WSZ_];
  for (int i = 0; i < WSZ_; ++i) used[i] = false;
  int mrm = 0, picked = 0;
  for (int ii = 0; ii < WSZ_ - 1; ++ii) {
    const int e = id[ii];
    if (picked < budget && !used[e] && !used[e + 1]) {
      used[e] = used[e + 1] = true;
      mrm |= (1 << (e + 1));
      ++picked;
    }
  }
  mrMask[win] = mrm;
  keptCnt[win] = WSZ_ - picked;
}

// ---------------------------------------------------------------------------
// K3: per-batch exclusive prefix over window kept-counts (tiny)
// ---------------------------------------------------------------------------
__global__ void k_scan_windows(const int* __restrict__ keptCnt,
                               int* __restrict__ outOff)
{
  const int b = threadIdx.x;
  if (b >= B_) return;
  int off = 0;
  for (int w = 0; w < NWIN_; ++w) {
    outOff[b * NWIN_ + w] = off;
    off += keptCnt[b * NWIN_ + w];
  }
}

// ---------------------------------------------------------------------------
// K4: emit z_new rows + lens_new.  grid: B*NWIN blocks, 256 threads.
// ---------------------------------------------------------------------------
__global__ __launch_bounds__(256) void k_emit(
    const float* __restrict__ z, const int* __restrict__ lens,
    const int* __restrict__ mrMask, const int* __restrict__ outOff,
    float* __restrict__ out, int TL)
{
  const int bw = blockIdx.x;
  const int b = bw / NWIN_, w = bw % NWIN_;
  const int tid = threadIdx.x;
  const int mrm = mrMask[bw];
  int p = outOff[bw];
  const int t0 = w * WSZ_;

  const float* zb = z + (long)b * T_ * D_;
  const int* lb = lens + b * T_;
  float* zout = out;
  float* lout = out + (long)B_ * TL * D_;

  for (int i = 0; i < WSZ_; ++i) {
    if ((mrm >> i) & 1) continue;
    if (p >= TL) return;
    const int t = t0 + i;
    const bool ab = (i < WSZ_ - 1) && ((mrm >> (i + 1)) & 1);
    float4 o = *(const float4*)(zb + (long)t * D_ + tid * 4);
    if (ab) {
      const float wi = (float)lb[t], wj = (float)lb[t + 1];
      const float s = wi + wj;
      const float4 zj = *(const float4*)(zb + (long)(t + 1) * D_ + tid * 4);
      o.x = (o.x * wi + zj.x * wj) / s;
      o.y = (o.y * wi + zj.y * wj) / s;
      o.z = (o.z * wi + zj.z * wj) / s;
      o.w = (o.w * wi + zj.w * wj) / s;
      if (tid == 0) lout[(long)b * TL + p] = s;
    } else {
      if (tid == 0) lout[(long)b * TL + p] = (float)lb[t];
    }
    *(float4*)(zout + ((long)b * TL + p) * D_ + tid * 4) = o;
    ++p;
  }
}

// ---------------------------------------------------------------------------
// K5: starts = exclusive cumsum of lens_new per row. grid: B blocks, 256 thr.
// ---------------------------------------------------------------------------
__global__ __launch_bounds__(256) void k_starts(
    const float* __restrict__ lens_f, float* __restrict__ starts, int TL)
{
  const int b = blockIdx.x;
  const int tid = threadIdx.x;
  const int lane = tid & 63, wv = tid >> 6;
  __shared__ float wsum[4];
  const float* lrow = lens_f + (long)b * TL;
  float* srow = starts + (long)b * TL;
  float carry = 0.0f;

  for (int c0 = 0; c0 < TL; c0 += 256) {
    const int j = c0 + tid;
    const float v = (j < TL) ? lrow[j] : 0.0f;
    float x = v;
#pragma unroll
    for (int d = 1; d < 64; d <<= 1) {
      const float o = __shfl_up(x, d);
      if (lane >= d) x += o;
    }
    if (lane == 63) wsum[wv] = x;
    __syncthreads();
    float pre = 0.0f;
    if (wv > 0) pre += wsum[0];
    if (wv > 1) pre += wsum[1];
    if (wv > 2) pre += wsum[2];
    const float tot = wsum[0] + wsum[1] + wsum[2] + wsum[3];
    if (j < TL) srow[j] = carry + pre + x - v;
    carry += tot;
    __syncthreads();
  }
}

// ---------------------------------------------------------------------------
extern "C" void kernel_launch(void* const* d_in, const int* in_sizes, int n_in,
                              void* d_out, int out_size, void* d_ws, size_t ws_size,
                              hipStream_t stream)
{
  const float* z    = (const float*)d_in[0];
  const int*   lens = (const int*)d_in[1];
  const float* W1   = (const float*)d_in[2];
  const float* W2   = (const float*)d_in[3];
  const int*   tlp  = (const int*)d_in[4];

  float* out = (float*)d_out;
  const int TL = out_size / (B_ * (D_ + 2));   // 6144

  double* sims  = (double*)d_ws;
  int* mrMask = (int*)((char*)d_ws + (size_t)B_ * NWIN_ * (WSZ_ - 1) * 8);
  int* kept   = mrMask + B_ * NWIN_;
  int* outOff = kept + B_ * NWIN_;

  hipLaunchKernelGGL(k_sims, dim3((B_ * T_) / 64), dim3(64), 0, stream,
                     z, W1, W2, sims);
  hipLaunchKernelGGL(k_pick, dim3((B_ * NWIN_ + 63) / 64), dim3(64), 0, stream,
                     sims, tlp, mrMask, kept);
  hipLaunchKernelGGL(k_scan_windows, dim3(1), dim3(64), 0, stream,
                     kept, outOff);
  hipLaunchKernelGGL(k_emit, dim3(B_ * NWIN_), dim3(256), 0, stream,
                     z, lens, mrMask, outOff, out, TL);
  hipLaunchKernelGGL(k_starts, dim3(B_), dim3(256), 0, stream,
                     out + (long)B_ * TL * D_,
                     out + (long)B_ * TL * D_ + (long)B_ * TL, TL);
}

// Round 4
// 271.070 us; speedup vs baseline: 1.5729x; 1.5729x over previous
//
#include <hip/hip_runtime.h>

#define B_ 8
#define T_ 8192
#define D_ 1024
#define GD_ 64
#define WSZ_ 16
#define NWIN_ (T_ / WSZ_)   // 512

// ---------------------------------------------------------------------------
// K1 (fused): sims of g = normalize(relu(z@W1)@W2).
// Block: 64 tokens x 64 gd, 256 threads = 4 waves. Waves split each 64-k
// chunk (16 k per wave), private f32 accumulators, deterministic in-LDS
// tree reduction. A-operand halved via shfl_xor(1) with gs-parity-permuted
// accumulator rows (all register indices compile-time). LDS slots
// XOR-swizzled (Zs by tok-octet, Ws by k-pair) -> ~2-way conflicts only.
// Precision: f32 FMA, two-level accumulation (4k-iter -> 16k chunk -> total,
// cross-wave pairwise f32 tree), f64 norms and sims. Same class as the
// validated R1-R3 pipeline.
// ---------------------------------------------------------------------------
__global__ __launch_bounds__(256) void k_sims(
    const float* __restrict__ z, const float* __restrict__ W1,
    const float* __restrict__ W2, double* __restrict__ sims_out)
{
  __shared__ float Zs[64][64];   // z chunk / H / G (slot ^= (tok>>3)&7)
  __shared__ float Ws[64][64];   // W1 chunk / W2 / scratch (slot ^= (k>>1)&7)

  const int tid = threadIdx.x;
  const int w = tid >> 6;        // wave 0..3
  const int lane = tid & 63;
  const int ts = lane >> 3;      // 0..7  -> token octet
  const int gs = lane & 7;       // 0..7  -> gd octet
  const int q = gs & 1;          // parity for A-shfl row permutation
  const long bt0 = (long)blockIdx.x * 64;
  const int rb0 = 8 * ts + 4 * q;        // rows for acc m=0..3
  const int rb1 = 8 * ts + 4 - 4 * q;    // rows for acc m=4..7

  float acc[8][8];
#pragma unroll
  for (int m = 0; m < 8; ++m)
#pragma unroll
    for (int n = 0; n < 8; ++n) acc[m][n] = 0.0f;

  // ---- helpers for 64x64 tile exchange through LDS (per-lane rows cover
  //      8ts..8ts+7, cols 8gs..8gs+7; q only permutes reg<->row mapping)
  auto partWrite = [&](float (*Ls)[64], float (&A)[8][8]) {
#pragma unroll
    for (int m = 0; m < 8; ++m) {
      const int row = (m < 4) ? (rb0 + m) : (rb1 + m - 4);
      *(float4*)&Ls[row][4 * ((2 * gs) ^ ts)] =
          make_float4(A[m][0], A[m][1], A[m][2], A[m][3]);
      *(float4*)&Ls[row][4 * ((2 * gs + 1) ^ ts)] =
          make_float4(A[m][4], A[m][5], A[m][6], A[m][7]);
    }
  };
  auto partAdd = [&](float (*Ls)[64], float (&A)[8][8]) {
#pragma unroll
    for (int m = 0; m < 8; ++m) {
      const int row = (m < 4) ? (rb0 + m) : (rb1 + m - 4);
      const float4 v0 = *(const float4*)&Ls[row][4 * ((2 * gs) ^ ts)];
      const float4 v1 = *(const float4*)&Ls[row][4 * ((2 * gs + 1) ^ ts)];
      A[m][0] += v0.x; A[m][1] += v0.y; A[m][2] += v0.z; A[m][3] += v0.w;
      A[m][4] += v1.x; A[m][5] += v1.y; A[m][6] += v1.z; A[m][7] += v1.w;
    }
  };

  // ---- inner 4k compute step: A via 4 b128 + shfl, B via 8 b128, 256 FMA
  auto step4 = [&](float (*As)[64], float (*Bs)[64], int kk,
                   float (&C)[8][8]) {
    const int c4k = kk >> 2;
    float A8[8][4];
#pragma unroll
    for (int m = 0; m < 4; ++m) {
      const float4 o = *(const float4*)&As[rb0 + m][4 * (c4k ^ ts)];
      A8[m][0] = o.x; A8[m][1] = o.y; A8[m][2] = o.z; A8[m][3] = o.w;
      A8[m + 4][0] = __shfl_xor(o.x, 1);
      A8[m + 4][1] = __shfl_xor(o.y, 1);
      A8[m + 4][2] = __shfl_xor(o.z, 1);
      A8[m + 4][3] = __shfl_xor(o.w, 1);
    }
    float bv[4][8];
#pragma unroll
    for (int jk = 0; jk < 4; ++jk) {
      const int kr = kk + jk;
      const int sw = (kr >> 1) & 7;
      const float4 b0 = *(const float4*)&Bs[kr][4 * ((2 * gs) ^ sw)];
      const float4 b1 = *(const float4*)&Bs[kr][4 * ((2 * gs + 1) ^ sw)];
      bv[jk][0] = b0.x; bv[jk][1] = b0.y; bv[jk][2] = b0.z; bv[jk][3] = b0.w;
      bv[jk][4] = b1.x; bv[jk][5] = b1.y; bv[jk][6] = b1.z; bv[jk][7] = b1.w;
    }
#pragma unroll
    for (int jk = 0; jk < 4; ++jk)
#pragma unroll
      for (int m = 0; m < 8; ++m)
#pragma unroll
        for (int n = 0; n < 8; ++n)
          C[m][n] = fmaf(A8[m][jk], bv[jk][n], C[m][n]);
  };

  // ================= phase A: H = z @ W1 (k split across waves) ===========
#pragma unroll 1
  for (int c = 0; c < 16; ++c) {
    const int k0 = c * 64;
    if (c) __syncthreads();       // previous chunk fully consumed
#pragma unroll
    for (int it = 0; it < 4; ++it) {
      const int idx = it * 256 + tid;
      const int row = idx >> 4, c4 = idx & 15;
      const float4 v = *(const float4*)(z + (bt0 + row) * D_ + k0 + 4 * c4);
      *(float4*)&Zs[row][4 * (c4 ^ ((row >> 3) & 7))] = v;
      const float4 u = *(const float4*)(W1 + (long)(k0 + row) * GD_ + 4 * c4);
      *(float4*)&Ws[row][4 * (c4 ^ ((row >> 1) & 7))] = u;
    }
    __syncthreads();
    float cacc[8][8];
#pragma unroll
    for (int m = 0; m < 8; ++m)
#pragma unroll
      for (int n = 0; n < 8; ++n) cacc[m][n] = 0.0f;
#pragma unroll
    for (int ii = 0; ii < 4; ++ii) step4(Zs, Ws, 16 * w + 4 * ii, cacc);
#pragma unroll
    for (int m = 0; m < 8; ++m)
#pragma unroll
      for (int n = 0; n < 8; ++n) acc[m][n] += cacc[m][n];
  }

  // ---- cross-wave reduce of H partials: ((w0+w2)+(w1+w3)), fixed order
  __syncthreads();
  if (w == 2) partWrite(Zs, acc);
  if (w == 3) partWrite(Ws, acc);
  __syncthreads();
  if (w == 0) partAdd(Zs, acc);
  if (w == 1) partAdd(Ws, acc);
  __syncthreads();
  if (w == 1) partWrite(Zs, acc);
  __syncthreads();
  if (w == 0) {
    partAdd(Zs, acc);
    // relu (f32, matches reference's f32 relu input)
#pragma unroll
    for (int m = 0; m < 8; ++m)
#pragma unroll
      for (int n = 0; n < 8; ++n) acc[m][n] = fmaxf(acc[m][n], 0.0f);
    partWrite(Zs, acc);           // H -> Zs
  }
  // stage W2 (all threads; Ws reads finished 2 barriers ago)
#pragma unroll
  for (int it = 0; it < 4; ++it) {
    const int idx = it * 256 + tid;
    const int row = idx >> 4, c4 = idx & 15;
    *(float4*)&Ws[row][4 * (c4 ^ ((row >> 1) & 7))] =
        *(const float4*)(W2 + row * GD_ + 4 * c4);
  }
  __syncthreads();

  // ================= phase B: G = H @ W2 (k split across waves) ===========
  float cb[8][8];
#pragma unroll
  for (int m = 0; m < 8; ++m)
#pragma unroll
    for (int n = 0; n < 8; ++n) cb[m][n] = 0.0f;
#pragma unroll
  for (int ii = 0; ii < 4; ++ii) step4(Zs, Ws, 16 * w + 4 * ii, cb);

  __syncthreads();                // all H reads done
  if (w == 2) partWrite(Zs, cb);
  if (w == 3) partWrite(Ws, cb);
  __syncthreads();
  if (w == 0) partAdd(Zs, cb);
  if (w == 1) partAdd(Ws, cb);
  __syncthreads();
  if (w == 1) partWrite(Zs, cb);
  __syncthreads();
  if (w == 0) {
    partAdd(Zs, cb);
    partWrite(Zs, cb);            // G -> Zs
  }
  __syncthreads();

  // ---- norms (f64) of G rows; den stored in Ws scratch
  double* den = (double*)&Ws[0][0];
  if (tid < 64) {
    const int t = tid;
    const int swt = (t >> 3) & 7;
    double ss = 0.0;
#pragma unroll
    for (int c4 = 0; c4 < 16; ++c4) {
      const float4 v = *(const float4*)&Zs[t][4 * (c4 ^ swt)];
      ss += (double)v.x * v.x + (double)v.y * v.y +
            (double)v.z * v.z + (double)v.w * v.w;
    }
    den[t] = sqrt(ss) + 1e-8;
  }
  __syncthreads();

  // ---- sims: 4 windows x 15 edges, f64 dot / (den*den)
  if (tid < 4 * (WSZ_ - 1)) {
    const int ww = tid / (WSZ_ - 1), e = tid % (WSZ_ - 1);
    const int t = ww * WSZ_ + e;
    const int swa = (t >> 3) & 7, swb = ((t + 1) >> 3) & 7;
    double s = 0.0;
#pragma unroll
    for (int c4 = 0; c4 < 16; ++c4) {
      const float4 a = *(const float4*)&Zs[t][4 * (c4 ^ swa)];
      const float4 b = *(const float4*)&Zs[t + 1][4 * (c4 ^ swb)];
      s += (double)a.x * b.x + (double)a.y * b.y +
           (double)a.z * b.z + (double)a.w * b.w;
    }
    sims_out[((long)blockIdx.x * 4 + ww) * (WSZ_ - 1) + e] =
        s / (den[t] * den[t + 1]);
  }
}

// ---------------------------------------------------------------------------
// K2: per-window stable sort + budgeted greedy pick. 1 thread per window.
// ---------------------------------------------------------------------------
__global__ __launch_bounds__(64) void k_pick(
    const double* __restrict__ sims, const int* __restrict__ tlptr,
    int* __restrict__ mrMask, int* __restrict__ keptCnt)
{
  const int win = blockIdx.x * 64 + threadIdx.x;
  if (win >= B_ * NWIN_) return;
  const int w = win % NWIN_;

  const int tl = tlptr[0];
  const int mn = T_ - tl;
  const int base = mn / NWIN_, extra = mn % NWIN_;
  int budget = base + (w < extra ? 1 : 0);
  if (budget > WSZ_ / 2) budget = WSZ_ / 2;
  if (budget < 0) budget = 0;

  double v[WSZ_ - 1];
  int id[WSZ_ - 1];
  for (int e = 0; e < WSZ_ - 1; ++e) {
    v[e] = sims[(long)win * (WSZ_ - 1) + e];
    id[e] = e;
  }
  for (int i = 1; i < WSZ_ - 1; ++i) {
    const double dv = v[i]; const int di = id[i];
    int j = i - 1;
    while (j >= 0 && v[j] < dv) { v[j + 1] = v[j]; id[j + 1] = id[j]; --j; }
    v[j + 1] = dv; id[j + 1] = di;
  }
  bool used[WSZ_];
  for (int i = 0; i < WSZ_; ++i) used[i] = false;
  int mrm = 0, picked = 0;
  for (int ii = 0; ii < WSZ_ - 1; ++ii) {
    const int e = id[ii];
    if (picked < budget && !used[e] && !used[e + 1]) {
      used[e] = used[e + 1] = true;
      mrm |= (1 << (e + 1));
      ++picked;
    }
  }
  mrMask[win] = mrm;
  keptCnt[win] = WSZ_ - picked;
}

// ---------------------------------------------------------------------------
// K3: per-batch exclusive prefix over window kept-counts (tiny)
// ---------------------------------------------------------------------------
__global__ void k_scan_windows(const int* __restrict__ keptCnt,
                               int* __restrict__ outOff)
{
  const int b = threadIdx.x;
  if (b >= B_) return;
  int off = 0;
  for (int w = 0; w < NWIN_; ++w) {
    outOff[b * NWIN_ + w] = off;
    off += keptCnt[b * NWIN_ + w];
  }
}

// ---------------------------------------------------------------------------
// K4: emit z_new rows + lens_new.  grid: B*NWIN blocks, 256 threads.
// ---------------------------------------------------------------------------
__global__ __launch_bounds__(256) void k_emit(
    const float* __restrict__ z, const int* __restrict__ lens,
    const int* __restrict__ mrMask, const int* __restrict__ outOff,
    float* __restrict__ out, int TL)
{
  const int bw = blockIdx.x;
  const int b = bw / NWIN_, w = bw % NWIN_;
  const int tid = threadIdx.x;
  const int mrm = mrMask[bw];
  int p = outOff[bw];
  const int t0 = w * WSZ_;

  const float* zb = z + (long)b * T_ * D_;
  const int* lb = lens + b * T_;
  float* zout = out;
  float* lout = out + (long)B_ * TL * D_;

  for (int i = 0; i < WSZ_; ++i) {
    if ((mrm >> i) & 1) continue;
    if (p >= TL) return;
    const int t = t0 + i;
    const bool ab = (i < WSZ_ - 1) && ((mrm >> (i + 1)) & 1);
    float4 o = *(const float4*)(zb + (long)t * D_ + tid * 4);
    if (ab) {
      const float wi = (float)lb[t], wj = (float)lb[t + 1];
      const float s = wi + wj;
      const float4 zj = *(const float4*)(zb + (long)(t + 1) * D_ + tid * 4);
      o.x = (o.x * wi + zj.x * wj) / s;
      o.y = (o.y * wi + zj.y * wj) / s;
      o.z = (o.z * wi + zj.z * wj) / s;
      o.w = (o.w * wi + zj.w * wj) / s;
      if (tid == 0) lout[(long)b * TL + p] = s;
    } else {
      if (tid == 0) lout[(long)b * TL + p] = (float)lb[t];
    }
    *(float4*)(zout + ((long)b * TL + p) * D_ + tid * 4) = o;
    ++p;
  }
}

// ---------------------------------------------------------------------------
// K5: starts = exclusive cumsum of lens_new per row. grid: B blocks, 256 thr.
// ---------------------------------------------------------------------------
__global__ __launch_bounds__(256) void k_starts(
    const float* __restrict__ lens_f, float* __restrict__ starts, int TL)
{
  const int b = blockIdx.x;
  const int tid = threadIdx.x;
  const int lane = tid & 63, wv = tid >> 6;
  __shared__ float wsum[4];
  const float* lrow = lens_f + (long)b * TL;
  float* srow = starts + (long)b * TL;
  float carry = 0.0f;

  for (int c0 = 0; c0 < TL; c0 += 256) {
    const int j = c0 + tid;
    const float v = (j < TL) ? lrow[j] : 0.0f;
    float x = v;
#pragma unroll
    for (int d = 1; d < 64; d <<= 1) {
      const float o = __shfl_up(x, d);
      if (lane >= d) x += o;
    }
    if (lane == 63) wsum[wv] = x;
    __syncthreads();
    float pre = 0.0f;
    if (wv > 0) pre += wsum[0];
    if (wv > 1) pre += wsum[1];
    if (wv > 2) pre += wsum[2];
    const float tot = wsum[0] + wsum[1] + wsum[2] + wsum[3];
    if (j < TL) srow[j] = carry + pre + x - v;
    carry += tot;
    __syncthreads();
  }
}

// ---------------------------------------------------------------------------
extern "C" void kernel_launch(void* const* d_in, const int* in_sizes, int n_in,
                              void* d_out, int out_size, void* d_ws, size_t ws_size,
                              hipStream_t stream)
{
  const float* z    = (const float*)d_in[0];
  const int*   lens = (const int*)d_in[1];
  const float* W1   = (const float*)d_in[2];
  const float* W2   = (const float*)d_in[3];
  const int*   tlp  = (const int*)d_in[4];

  float* out = (float*)d_out;
  const int TL = out_size / (B_ * (D_ + 2));   // 6144

  double* sims  = (double*)d_ws;
  int* mrMask = (int*)((char*)d_ws + (size_t)B_ * NWIN_ * (WSZ_ - 1) * 8);
  int* kept   = mrMask + B_ * NWIN_;
  int* outOff = kept + B_ * NWIN_;

  hipLaunchKernelGGL(k_sims, dim3((B_ * T_) / 64), dim3(256), 0, stream,
                     z, W1, W2, sims);
  hipLaunchKernelGGL(k_pick, dim3((B_ * NWIN_ + 63) / 64), dim3(64), 0, stream,
                     sims, tlp, mrMask, kept);
  hipLaunchKernelGGL(k_scan_windows, dim3(1), dim3(64), 0, stream,
                     kept, outOff);
  hipLaunchKernelGGL(k_emit, dim3(B_ * NWIN_), dim3(256), 0, stream,
                     z, lens, mrMask, outOff, out, TL);
  hipLaunchKernelGGL(k_starts, dim3(B_), dim3(256), 0, stream,
                     out + (long)B_ * TL * D_,
                     out + (long)B_ * TL * D_ + (long)B_ * TL, TL);
}